// Round 8
// baseline (9417.727 us; speedup 1.0000x reference)
//
#include <hip/hip_runtime.h>
#include <cmath>

// ---------------------------------------------------------------------------
// DeepAR sampling on MI355X. Round 8: persistent decoder v2 (XCD-local).
//  - Round-7 fusion kept, but ALL h2/tgt dataflow is partitioned inside one
//    intended XCD (b&7): GRU tiles, heads, and next-step reads for samples
//    [x*1024, x*1024+1024) all live on XCD x. Coherence = write-through L1
//    -> shared per-XCD L2; no __threadfence (round 7: fences wiped L2 ->
//    3.07 GB HBM/launch, 568 GB/s latency-bound).
//  - Barriers: 64-block XCD-local flag barrier (release store + acquire
//    polls; round-3 proven; acquire polls don't wipe L2 per round-7 data).
//  - Mapping safety: s_getreg(HW_REG_XCC_ID) + per-group atomicOr mask; if a
//    group spans >1 physical XCD -> that group enables round-7 fences.
//  - tgt-barrier deferred past next K-loop: head RNG overlaps next GEMM.
//  - GRU MFMA order + per-sample head dot order bit-identical to round 6.
// ---------------------------------------------------------------------------

#define JAX_PARTITIONABLE 1

#define HIDDEN 512
#define EMB 40
#define HIST 336
#define PRED 48
#define S_N 8192
#define ENC_BLOCKS 48
#define DEC_BLOCKS 512

#define HPLANE (8192 * 512)     // shorts per h split plane
#define WPLANE (1536 * 512)     // shorts per W split plane
#define INV4096 (1.0f / 4096.0f)

typedef __attribute__((ext_vector_type(8))) _Float16 half8;
typedef __attribute__((ext_vector_type(4))) float f32x4;

// ------------------------------- threefry ----------------------------------
struct KeyPair { unsigned a, b; };

__device__ __forceinline__ unsigned rotl32_(unsigned v, unsigned s) {
  return (v << s) | (v >> (32u - s));
}

__device__ __forceinline__ KeyPair tf2x32(KeyPair k, unsigned x0, unsigned x1) {
  unsigned ks0 = k.a, ks1 = k.b, ks2 = ks0 ^ ks1 ^ 0x1BD11BDAu;
  x0 += ks0; x1 += ks1;
#define TF_R(r) { x0 += x1; x1 = rotl32_(x1, r); x1 ^= x0; }
  TF_R(13u) TF_R(15u) TF_R(26u) TF_R(6u)  x0 += ks1; x1 += ks2 + 1u;
  TF_R(17u) TF_R(29u) TF_R(16u) TF_R(24u) x0 += ks2; x1 += ks0 + 2u;
  TF_R(13u) TF_R(15u) TF_R(26u) TF_R(6u)  x0 += ks0; x1 += ks1 + 3u;
  TF_R(17u) TF_R(29u) TF_R(16u) TF_R(24u) x0 += ks1; x1 += ks2 + 4u;
  TF_R(13u) TF_R(15u) TF_R(26u) TF_R(6u)  x0 += ks2; x1 += ks0 + 5u;
#undef TF_R
  KeyPair r; r.a = x0; r.b = x1; return r;
}

__device__ __forceinline__ void split2_(KeyPair key, KeyPair& r0, KeyPair& r1) {
#if JAX_PARTITIONABLE
  r0 = tf2x32(key, 0u, 0u);
  r1 = tf2x32(key, 0u, 1u);
#else
  KeyPair p0 = tf2x32(key, 0u, 2u);
  KeyPair p1 = tf2x32(key, 1u, 3u);
  r0.a = p0.a; r0.b = p1.a;
  r1.a = p0.b; r1.b = p1.b;
#endif
}

__device__ __forceinline__ void split3_(KeyPair key, KeyPair& r0, KeyPair& r1, KeyPair& r2) {
#if JAX_PARTITIONABLE
  r0 = tf2x32(key, 0u, 0u);
  r1 = tf2x32(key, 0u, 1u);
  r2 = tf2x32(key, 0u, 2u);
#else
  KeyPair p0 = tf2x32(key, 0u, 3u);
  KeyPair p1 = tf2x32(key, 1u, 4u);
  KeyPair p2 = tf2x32(key, 2u, 5u);
  r0.a = p0.a; r0.b = p1.a;
  r1.a = p2.a; r1.b = p0.b;
  r2.a = p1.b; r2.b = p2.b;
#endif
}

__device__ __forceinline__ unsigned scalar_bits_(KeyPair key) {
#if JAX_PARTITIONABLE
  KeyPair p = tf2x32(key, 0u, 0u);
  return p.a ^ p.b;
#else
  return tf2x32(key, 0u, 0u).a;
#endif
}

__device__ __forceinline__ unsigned batch_bits_8192_(KeyPair key, int s) {
#if JAX_PARTITIONABLE
  KeyPair p = tf2x32(key, 0u, (unsigned)s);
  return p.a ^ p.b;
#else
  if (s < 4096) return tf2x32(key, (unsigned)s, (unsigned)(4096 + s)).a;
  return tf2x32(key, (unsigned)(s - 4096), (unsigned)s).b;
#endif
}

__device__ __forceinline__ KeyPair subkey_of_8192_(KeyPair key, int s) {
#if JAX_PARTITIONABLE
  return tf2x32(key, 0u, (unsigned)s);
#else
  KeyPair r;
  if (s < 4096) {
    r.a = tf2x32(key, (unsigned)(2 * s),     (unsigned)(8192 + 2 * s)).a;
    r.b = tf2x32(key, (unsigned)(2 * s + 1), (unsigned)(8192 + 2 * s + 1)).a;
  } else {
    int m = 2 * s - 8192;
    r.a = tf2x32(key, (unsigned)m,       (unsigned)(m + 8192)).b;
    r.b = tf2x32(key, (unsigned)(m + 1), (unsigned)(m + 1 + 8192)).b;
  }
  return r;
#endif
}

// ------------------------- fp32 numerics (XLA-matched) ---------------------
__device__ __forceinline__ float acc_logf_(float x) {
  return (float)log((double)x);
}
__device__ __forceinline__ float acc_expf_(float x) {
  return (float)exp((double)x);
}

__device__ __forceinline__ float bits_to_uniform01_(unsigned bits) {
  return __uint_as_float((bits >> 9) | 0x3F800000u) - 1.0f;
}

__device__ __forceinline__ float xla_log1pf_(float t) {
  #pragma clang fp contract(off)
  float small_ = (1.0f + (-0.5f) * t) * t;
  float large_ = acc_logf_(t + 1.0f);
  return (fabsf(t) < 1e-4f) ? small_ : large_;
}

__device__ float xla_erfinv_(float x) {
  #pragma clang fp contract(off)
  float w = -xla_log1pf_(-(x * x));
  float p;
  if (w < 5.0f) {
    float ww = w - 2.5f;
    p = 2.81022636e-08f;
    p = 3.43273939e-07f + p * ww;
    p = -3.5233877e-06f + p * ww;
    p = -4.39150654e-06f + p * ww;
    p = 0.00021858087f + p * ww;
    p = -0.00125372503f + p * ww;
    p = -0.00417768164f + p * ww;
    p = 0.246640727f + p * ww;
    p = 1.50140941f + p * ww;
  } else {
    float ww = sqrtf(w) - 3.0f;
    p = -0.000200214257f;
    p = 0.000100950558f + p * ww;
    p = 0.00134934322f + p * ww;
    p = -0.00367342844f + p * ww;
    p = 0.00573950773f + p * ww;
    p = -0.0076224613f + p * ww;
    p = 0.00943887047f + p * ww;
    p = 1.00167406f + p * ww;
    p = 2.83297682f + p * ww;
  }
  return p * x;
}

__device__ float bits_to_normal_(unsigned bits) {
  #pragma clang fp contract(off)
  const float lo = __uint_as_float(0xBF7FFFFFu);
  float f = bits_to_uniform01_(bits);
  float u = f * 2.0f + lo;
  u = fmaxf(lo, u);
  return __uint_as_float(0x3FB504F3u) * xla_erfinv_(u);
}

__device__ __forceinline__ float softplus_(float x) {
  #pragma clang fp contract(off)
  float amax = fmaxf(x, 0.0f);
  float e = acc_expf_(-fabsf(x));
  return amax + xla_log1pf_(e);
}

__device__ __forceinline__ float sigmoid_(float v) { return 1.0f / (1.0f + expf(-v)); }

// fp16 split helpers (round-to-nearest-even via cast)
__device__ __forceinline__ unsigned short f2h_(float f) {
  _Float16 h = (_Float16)f;
  return __builtin_bit_cast(unsigned short, h);
}
__device__ __forceinline__ float h2f_(unsigned short b) {
  return (float)__builtin_bit_cast(_Float16, b);
}

// ------------------------- gamma / student-t sampler -----------------------
__device__ float gamma_sample_(KeyPair gkey, float alpha) {
  #pragma clang fp contract(off)
  const float third = 0.33333334f;
  float d = alpha - third;
  float c = third / sqrtf(d);
  KeyPair key, boost_sub;
  split2_(gkey, key, boost_sub);
  (void)boost_sub;
  float X = 0.0f, V = 1.0f, U = 2.0f;
  for (int guard = 0; guard < 1024; guard++) {
    float X2 = X * X;
    float sq = 1.0f - 0.0331f * (X2 * X2);
    bool cont = false;
    if (U >= sq) {
      float lhs = acc_logf_(U);
      float rhs = (X * 0.5f) + (d * ((1.0f - V) + acc_logf_(V)));
      cont = (lhs >= rhs);
    }
    if (!cont) break;
    KeyPair nkey, xkey, Ukey;
    split3_(key, nkey, xkey, Ukey);
    key = nkey;
    float x, v;
    KeyPair kk = xkey;
    do {
      KeyPair knew, sub;
      split2_(kk, knew, sub);
      kk = knew;
      x = bits_to_normal_(scalar_bits_(sub));
      v = 1.0f + x * c;
    } while (v <= 0.0f);
    X = x * x;
    V = (v * v) * v;
    U = bits_to_uniform01_(scalar_bits_(Ukey));
  }
  return d * V;
}

__device__ float sample_t_eps_(int k, int s, float df) {
  #pragma clang fp contract(off)
  KeyPair base; base.a = 0u; base.b = 42u;
  KeyPair tkey = tf2x32(base, 0u, (unsigned)k);
  KeyPair key_n, key_g;
  split2_(tkey, key_n, key_g);
  float n = bits_to_normal_(batch_bits_8192_(key_n, s));
  KeyPair gkey = subkey_of_8192_(key_g, s);
  float half_df = df * 0.5f;
  float g = gamma_sample_(gkey, half_df);
  return n * sqrtf(half_df / g);
}

// ------------------------------- kernels -----------------------------------

__global__ __launch_bounds__(256) void prep_kernel(
    const float* __restrict__ x, const float* __restrict__ x_mark,
    const float* __restrict__ y_mark, const float* __restrict__ W_emb,
    const float* __restrict__ b_emb, float* __restrict__ scale_p,
    float* __restrict__ tfe, float* __restrict__ emb_y,
    unsigned* __restrict__ eflags, unsigned* __restrict__ dflags) {
  int tid = threadIdx.x;
  if (tid == 0) {
    float s = 0.0f;
    for (int t = 0; t < HIST; t++) s += fabsf(x[t]);
    float m = s / 336.0f;
    scale_p[0] = fmaxf(m, 1e-5f);
  }
  for (int i = tid; i < ENC_BLOCKS * 16; i += 256) eflags[i] = 0u;
  for (int i = tid; i < DEC_BLOCKS * 16 + 16; i += 256) dflags[i] = 0u;
  for (int idx = tid; idx < HIST * EMB; idx += 256) {
    int t = idx / EMB, e = idx % EMB;
    float a = b_emb[e];
    for (int f = 0; f < 4; f++) a += x_mark[t * 4 + f] * W_emb[e * 4 + f];
    tfe[idx] = a;
  }
  for (int idx = tid; idx < PRED * EMB; idx += 256) {
    int kk = idx / EMB, e = idx % EMB;
    float a = b_emb[e];
    for (int f = 0; f < 4; f++) a += y_mark[kk * 4 + f] * W_emb[e * 4 + f];
    emb_y[idx] = a;
  }
}

__global__ __launch_bounds__(256) void enc_gi_kernel(
    const float* __restrict__ x, const float* __restrict__ tfe,
    const float* __restrict__ W_ih, const float* __restrict__ b_ih,
    const float* __restrict__ scale_p, float* __restrict__ enc_gi) {
  __shared__ float fe[EMB];
  __shared__ float xs_s;
  int t = blockIdx.x;
  int tid = threadIdx.x;
  if (tid < EMB) fe[tid] = tfe[t * EMB + tid];
  if (tid == 0) xs_s = x[t] / scale_p[0];
  __syncthreads();
  float xs = xs_s;
  for (int r = tid; r < 3 * HIDDEN; r += 256) {
    const float* wr = W_ih + (size_t)r * 41;
    float a = b_ih[r] + wr[0] * xs;
    #pragma unroll
    for (int e = 0; e < EMB; e++) a += wr[1 + e] * fe[e];
    enc_gi[(size_t)t * 1536 + r] = a;
  }
}

__global__ __launch_bounds__(256) void giy_kernel(
    const float* __restrict__ emb_y, const float* __restrict__ W_ih,
    const float* __restrict__ b_ih, float* __restrict__ giy) {
  __shared__ float fe[EMB];
  int k = blockIdx.x;
  int tid = threadIdx.x;
  if (tid < EMB) fe[tid] = emb_y[k * EMB + tid];
  __syncthreads();
  for (int r = tid; r < 3 * HIDDEN; r += 256) {
    const float* wr = W_ih + (size_t)r * 41;
    float a = b_ih[r];
    #pragma unroll
    for (int e = 0; e < EMB; e++) a += wr[1 + e] * fe[e];
    giy[(size_t)k * 1536 + r] = a;
  }
}

// W_hh -> 2 fp16 split planes: Wr[sp][jb*96 + g*32 + jl][k], row = g*512+jb*32+jl
__global__ __launch_bounds__(256) void wsplit_kernel(
    const float* __restrict__ W_hh, unsigned short* __restrict__ Wr) {
  int row = blockIdx.x;                 // 0..1535
  int g = row >> 9;
  int jg = row & 511;
  int jb = jg >> 5, jl = jg & 31;
  size_t dst = ((size_t)jb * 96 + g * 32 + jl) * 512;
  for (int k = threadIdx.x; k < 512; k += 256) {
    float w = W_hh[(size_t)row * 512 + k];
    unsigned short g0 = f2h_(w);
    float r1 = (w - h2f_(g0)) * 4096.0f;
    unsigned short g1 = f2h_(r1);
    Wr[dst + k] = g0;
    Wr[WPLANE + dst + k] = g1;
  }
}

// split h_T (512) into sT[2][512] fp16 planes
__global__ __launch_bounds__(256) void hsplit_kernel(
    const float* __restrict__ h_T, unsigned short* __restrict__ sT) {
  int i = threadIdx.x;
  for (int j = i; j < 512; j += 256) {
    float v = h_T[j];
    unsigned short f0 = f2h_(v);
    float r1 = (v - h2f_(f0)) * 4096.0f;
    sT[j] = f0;
    sT[512 + j] = f2h_(r1);
  }
}

// broadcast sT rows into h2[2][8192][512]
__global__ __launch_bounds__(128) void h2bcast_kernel(
    const unsigned short* __restrict__ sT, unsigned short* __restrict__ h2) {
  int row = blockIdx.x;
  int tid = threadIdx.x;
  int sp = tid >> 6, c = tid & 63;
  ((uint4*)(h2 + (size_t)sp * HPLANE + (size_t)row * 512))[c] =
      ((const uint4*)(sT + sp * 512))[c];
}

// persistent encoder GRU; round-3 flag-array grid barrier (unchanged)
__global__ __launch_bounds__(256) void enc_gru_kernel(
    const float* __restrict__ enc_gi, const float* __restrict__ W_hh,
    const float* __restrict__ b_hh, float* __restrict__ ghbuf,
    unsigned* __restrict__ flags, float* __restrict__ h_T) {
  __shared__ __align__(16) float hs[HIDDEN];
  int tid = threadIdx.x;
  int gtid = blockIdx.x * 256 + tid;
  int row = gtid >> 3;
  int sub = gtid & 7;

  float w[64];
  const float* wp = W_hh + (size_t)row * HIDDEN + sub * 64;
  #pragma unroll
  for (int i = 0; i < 16; i++) {
    float4 v = *(const float4*)(wp + 4 * i);
    w[4 * i + 0] = v.x; w[4 * i + 1] = v.y; w[4 * i + 2] = v.z; w[4 * i + 3] = v.w;
  }
  if (tid < 128) *(float4*)&hs[tid * 4] = make_float4(0.f, 0.f, 0.f, 0.f);
  float bhr0 = b_hh[tid],       bhz0 = b_hh[512 + tid],  bhn0 = b_hh[1024 + tid];
  float bhr1 = b_hh[256 + tid], bhz1 = b_hh[768 + tid],  bhn1 = b_hh[1280 + tid];
  __syncthreads();

  for (int t = 0; t < HIST; t++) {
    float p = 0.0f;
    const float4* hv = (const float4*)&hs[sub * 64];
    #pragma unroll
    for (int i = 0; i < 16; i++) {
      float4 v = hv[i];
      p += w[4 * i + 0] * v.x + w[4 * i + 1] * v.y +
           w[4 * i + 2] * v.z + w[4 * i + 3] * v.w;
    }
    p += __shfl_xor(p, 1, 64);
    p += __shfl_xor(p, 2, 64);
    p += __shfl_xor(p, 4, 64);
    int par = t & 1;
    if (sub == 0)
      __hip_atomic_store(&ghbuf[par * 1536 + row], p, __ATOMIC_RELAXED,
                         __HIP_MEMORY_SCOPE_AGENT);
    __syncthreads();
    if (tid == 0)
      __hip_atomic_store(&flags[blockIdx.x * 16], (unsigned)(t + 1),
                         __ATOMIC_RELEASE, __HIP_MEMORY_SCOPE_AGENT);
    if (tid < ENC_BLOCKS) {
      while (__hip_atomic_load(&flags[tid * 16], __ATOMIC_ACQUIRE,
                               __HIP_MEMORY_SCOPE_AGENT) < (unsigned)(t + 1))
        __builtin_amdgcn_s_sleep(1);
    }
    __syncthreads();
    float hn0, hn1;
    {
      int j = tid;
      float ghr = __hip_atomic_load(&ghbuf[par * 1536 + j], __ATOMIC_RELAXED, __HIP_MEMORY_SCOPE_AGENT);
      float ghz = __hip_atomic_load(&ghbuf[par * 1536 + 512 + j], __ATOMIC_RELAXED, __HIP_MEMORY_SCOPE_AGENT);
      float ghn = __hip_atomic_load(&ghbuf[par * 1536 + 1024 + j], __ATOMIC_RELAXED, __HIP_MEMORY_SCOPE_AGENT);
      float gir = enc_gi[(size_t)t * 1536 + j];
      float giz = enc_gi[(size_t)t * 1536 + 512 + j];
      float gin = enc_gi[(size_t)t * 1536 + 1024 + j];
      float r = sigmoid_(gir + (ghr + bhr0));
      float z = sigmoid_(giz + (ghz + bhz0));
      float n = tanhf(gin + r * (ghn + bhn0));
      hn0 = (1.0f - z) * n + z * hs[j];
    }
    {
      int j = tid + 256;
      float ghr = __hip_atomic_load(&ghbuf[par * 1536 + j], __ATOMIC_RELAXED, __HIP_MEMORY_SCOPE_AGENT);
      float ghz = __hip_atomic_load(&ghbuf[par * 1536 + 512 + j], __ATOMIC_RELAXED, __HIP_MEMORY_SCOPE_AGENT);
      float ghn = __hip_atomic_load(&ghbuf[par * 1536 + 1024 + j], __ATOMIC_RELAXED, __HIP_MEMORY_SCOPE_AGENT);
      float gir = enc_gi[(size_t)t * 1536 + j];
      float giz = enc_gi[(size_t)t * 1536 + 512 + j];
      float gin = enc_gi[(size_t)t * 1536 + 1024 + j];
      float r = sigmoid_(gir + (ghr + bhr1));
      float z = sigmoid_(giz + (ghz + bhz1));
      float n = tanhf(gin + r * (ghn + bhn1));
      hn1 = (1.0f - z) * n + z * hs[j];
    }
    hs[tid] = hn0;
    hs[tid + 256] = hn1;
    __syncthreads();
  }
  if (blockIdx.x == 0 && tid < 128)
    *(float4*)&h_T[tid * 4] = *(float4*)&hs[tid * 4];
}

// ---------------------------------------------------------------------------
// XCD-local flag barrier for 64 intended-XCD-mate blocks (b&7 == x).
// fence_on: round-7 __threadfence pair fallback for broken XCD mapping.
// ---------------------------------------------------------------------------
__device__ __forceinline__ void gbar2_(unsigned* dflags, int b, int x, int tid,
                                       unsigned epoch, bool fence_on) {
  __syncthreads();
  if (tid == 0) {
    if (fence_on) __threadfence();
    __hip_atomic_store(&dflags[b * 16], epoch, __ATOMIC_RELEASE,
                       __HIP_MEMORY_SCOPE_AGENT);
  }
  if (tid < 64) {
    while (__hip_atomic_load(&dflags[(x + 8 * tid) * 16], __ATOMIC_ACQUIRE,
                             __HIP_MEMORY_SCOPE_AGENT) < epoch)
      __builtin_amdgcn_s_sleep(1);
  }
  __syncthreads();
  if (fence_on) {
    if (tid == 0) __threadfence();
    __syncthreads();
  }
}

// ---------------------------------------------------------------------------
// Persistent decoder v2: 48 steps, XCD-local. 512 blocks x 256 threads.
// Block b: x=b&7, slot=b>>3, jb=slot>>2, mp=slot&3; tiles mb=x*8+mp*2+{0,1}.
// Heads: samples x*1024 + slot*16 .. +16 (XCD-local), round-6 dot order.
// tgt barrier deferred past tile-0 K-loop -> head RNG overlaps next GEMM.
// ---------------------------------------------------------------------------
__global__ __launch_bounds__(256, 2) void dec_persistent(
    unsigned short* __restrict__ h2_a, unsigned short* __restrict__ h2_b,
    const unsigned short* __restrict__ Wr, const float* __restrict__ giy,
    const float* __restrict__ b_hh, const float* __restrict__ W_ih,
    const float* __restrict__ x, const float* __restrict__ W_df,
    const float* __restrict__ b_df, const float* __restrict__ W_loc,
    const float* __restrict__ b_loc, const float* __restrict__ W_sc,
    const float* __restrict__ b_sc, const float* __restrict__ scale_p,
    float* __restrict__ tgt, float* __restrict__ out,
    unsigned* __restrict__ dflags, unsigned* __restrict__ xmask) {
  __shared__ unsigned short As[2][2][128][32];   // [buf][plane][row][col]
  __shared__ int fence_s;
  int b = blockIdx.x;
  int tid = threadIdx.x;
  int x_ = b & 7, slot = b >> 3;         // slot 0..63
  int jb = slot >> 2;                    // 0..15
  int mp = slot & 3;                     // 0..3
  int lane = tid & 63;
  int wave = tid >> 6;
  int wm = wave >> 1, wn = wave & 1;
  int q = lane >> 4, c = lane & 15;

  // physical-XCD mapping check: per-group OR of XCC_IDs
  if (tid == 0) {
    unsigned xcc = __builtin_amdgcn_s_getreg(6164) & 0xfu;  // HW_REG_XCC_ID
    __hip_atomic_fetch_or(&xmask[x_], 1u << (xcc & 31u), __ATOMIC_RELAXED,
                          __HIP_MEMORY_SCOPE_AGENT);
  }
  gbar2_(dflags, b, x_, tid, 1u, true);   // conservative first barrier
  if (tid == 0) {
    unsigned m = __hip_atomic_load(&xmask[x_], __ATOMIC_RELAXED,
                                   __HIP_MEMORY_SCOPE_AGENT);
    fence_s = (__popc(m) != 1) ? 1 : 0;
  }
  __syncthreads();
  bool fence_on = (fence_s != 0);

  float xlast = x[HIST - 1];
  float scale = scale_p[0];

  // per-thread A staging map
  int asp[4], arow[4], acol[4];
  #pragma unroll
  for (int r = 0; r < 4; r++) {
    int a = r * 256 + tid;
    asp[r] = a >> 9;
    int rem = a & 511;
    arow[r] = rem >> 2;
    acol[r] = rem & 3;
  }
  const unsigned short* Bbase =
      Wr + ((size_t)jb * 96 + wn * 16 + c) * 512 + q * 8;

  int jcol = jb * 32 + wn * 16 + c;
  float w0r = W_ih[(size_t)jcol * 41];
  float w0z = W_ih[(size_t)(512 + jcol) * 41];
  float w0n = W_ih[(size_t)(1024 + jcol) * 41];
  float bhr = b_hh[jcol], bhz = b_hh[512 + jcol], bhn = b_hh[1024 + jcol];

  unsigned ep = 2u;
  for (int k = 0; k < PRED; k++) {
    const unsigned short* h2_in = (k & 1) ? h2_b : h2_a;
    unsigned short* h2_out = (k & 1) ? h2_a : h2_b;
    const float* giy_k = giy + (size_t)k * 1536;
    float gyr = giy_k[jcol], gyz = giy_k[512 + jcol], gyn = giy_k[1024 + jcol];

    // ---------------- phase A: GRU, two tiles (same jb) ----------------
    for (int m2 = 0; m2 < 2; m2++) {
      int mb = x_ * 8 + mp * 2 + m2;
      int s0 = mb * 128;

      f32x4 accm[4][3], accc[4][3];
      #pragma unroll
      for (int i = 0; i < 4; i++)
        #pragma unroll
        for (int g = 0; g < 3; g++) {
          accm[i][g] = (f32x4){0.f, 0.f, 0.f, 0.f};
          accc[i][g] = (f32x4){0.f, 0.f, 0.f, 0.f};
        }
      float hold[4][4];

      #pragma unroll
      for (int r = 0; r < 4; r++) {
        uint4 v = *(const uint4*)(h2_in + (size_t)asp[r] * HPLANE +
                                  (size_t)(s0 + arow[r]) * 512 + acol[r] * 8);
        *(uint4*)&As[0][asp[r]][arow[r]][(acol[r] ^ (arow[r] & 3)) * 8] = v;
      }
      half8 Bcur[3][2];
      #pragma unroll
      for (int g = 0; g < 3; g++) {
        Bcur[g][0] = *(const half8*)(Bbase + (size_t)g * 32 * 512);
        Bcur[g][1] = *(const half8*)(Bbase + WPLANE + (size_t)g * 32 * 512);
      }
      __syncthreads();

      int cur = 0;
      for (int kbi = 0; kbi < 16; kbi++) {
        int kb = kbi * 32;
        uint4 Areg[4];
        half8 Bn[3][2];
        if (kbi < 15) {
          #pragma unroll
          for (int r = 0; r < 4; r++)
            Areg[r] = *(const uint4*)(h2_in + (size_t)asp[r] * HPLANE +
                                      (size_t)(s0 + arow[r]) * 512 + kb + 32 +
                                      acol[r] * 8);
          #pragma unroll
          for (int g = 0; g < 3; g++) {
            Bn[g][0] = *(const half8*)(Bbase + (size_t)g * 32 * 512 + kb + 32);
            Bn[g][1] = *(const half8*)(Bbase + WPLANE + (size_t)g * 32 * 512 + kb + 32);
          }
        }
        if (kbi == jb) {
          int cc = wn * 16 + c;
          #pragma unroll
          for (int i = 0; i < 4; i++)
            #pragma unroll
            for (int reg = 0; reg < 4; reg++) {
              int m = wm * 64 + i * 16 + q * 4 + reg;
              int idx = (((cc >> 3) ^ (m & 3)) << 3) + (cc & 7);
              hold[i][reg] = h2f_(As[cur][0][m][idx]) +
                             h2f_(As[cur][1][m][idx]) * INV4096;
            }
        }
        #pragma unroll
        for (int i = 0; i < 4; i++) {
          int m = wm * 64 + i * 16 + c;
          half8 a0 = *(const half8*)&As[cur][0][m][(q ^ (c & 3)) * 8];
          half8 a1 = *(const half8*)&As[cur][1][m][(q ^ (c & 3)) * 8];
          #pragma unroll
          for (int g = 0; g < 3; g++) {
            accm[i][g] = __builtin_amdgcn_mfma_f32_16x16x32_f16(a0, Bcur[g][0], accm[i][g], 0, 0, 0);
            accc[i][g] = __builtin_amdgcn_mfma_f32_16x16x32_f16(a0, Bcur[g][1], accc[i][g], 0, 0, 0);
            accc[i][g] = __builtin_amdgcn_mfma_f32_16x16x32_f16(a1, Bcur[g][0], accc[i][g], 0, 0, 0);
          }
        }
        if (kbi < 15) {
          #pragma unroll
          for (int r = 0; r < 4; r++)
            *(uint4*)&As[cur ^ 1][asp[r]][arow[r]]
                      [(acol[r] ^ (arow[r] & 3)) * 8] = Areg[r];
          #pragma unroll
          for (int g = 0; g < 3; g++) {
            Bcur[g][0] = Bn[g][0];
            Bcur[g][1] = Bn[g][1];
          }
        }
        __syncthreads();
        cur ^= 1;
      }

      // tgt-barrier: deferred behind tile-0 K-loop (head k-1 overlap)
      if (m2 == 0 && k > 0) gbar2_(dflags, b, x_, tid, ep++, fence_on);

      // epilogue: gates + h update + fp16 2-split store
      #pragma unroll
      for (int i = 0; i < 4; i++) {
        #pragma unroll
        for (int reg = 0; reg < 4; reg++) {
          int s = s0 + wm * 64 + i * 16 + q * 4 + reg;
          float tg = (k == 0) ? xlast : tgt[s];
          size_t off = (size_t)s * 512 + jcol;
          float h_old = hold[i][reg];
          float ghr = accm[i][0][reg] + accc[i][0][reg] * INV4096;
          float ghz = accm[i][1][reg] + accc[i][1][reg] * INV4096;
          float ghn = accm[i][2][reg] + accc[i][2][reg] * INV4096;
          float gr = (gyr + w0r * tg) + (ghr + bhr);
          float gz = (gyz + w0z * tg) + (ghz + bhz);
          float gn_i = gyn + w0n * tg;
          float gn_h = ghn + bhn;
          float r_ = sigmoid_(gr);
          float z_ = sigmoid_(gz);
          float n_ = tanhf(gn_i + r_ * gn_h);
          float hn = (1.0f - z_) * n_ + z_ * h_old;
          unsigned short f0 = f2h_(hn);
          float r1 = (hn - h2f_(f0)) * 4096.0f;
          h2_out[off] = f0;
          h2_out[HPLANE + off] = f2h_(r1);
        }
      }
      __syncthreads();
    }

    gbar2_(dflags, b, x_, tid, ep++, fence_on);   // h2_out visible

    // ---------------- phase B: heads, 4 samples per wave (XCD-local) -----
    {
      #pragma clang fp contract(off)
      float wd[8], wl[8], ws[8];
      {
        float4 a0 = ((const float4*)W_df)[lane * 2];
        float4 a1 = ((const float4*)W_df)[lane * 2 + 1];
        wd[0] = a0.x; wd[1] = a0.y; wd[2] = a0.z; wd[3] = a0.w;
        wd[4] = a1.x; wd[5] = a1.y; wd[6] = a1.z; wd[7] = a1.w;
        float4 l0 = ((const float4*)W_loc)[lane * 2];
        float4 l1 = ((const float4*)W_loc)[lane * 2 + 1];
        wl[0] = l0.x; wl[1] = l0.y; wl[2] = l0.z; wl[3] = l0.w;
        wl[4] = l1.x; wl[5] = l1.y; wl[6] = l1.z; wl[7] = l1.w;
        float4 s0v = ((const float4*)W_sc)[lane * 2];
        float4 s1v = ((const float4*)W_sc)[lane * 2 + 1];
        ws[0] = s0v.x; ws[1] = s0v.y; ws[2] = s0v.z; ws[3] = s0v.w;
        ws[4] = s1v.x; ws[5] = s1v.y; ws[6] = s1v.z; ws[7] = s1v.w;
      }
      int sbase = x_ * 1024 + slot * 16 + wave * 4;
      float adf = 0.f, alo = 0.f, asc = 0.f;
      #pragma unroll
      for (int i = 0; i < 4; i++) {
        size_t base = (size_t)(sbase + i) * 512 + lane * 8;
        uint4 q0 = *(const uint4*)(h2_out + base);
        uint4 q1 = *(const uint4*)(h2_out + HPLANE + base);
        float xs[8];
        xs[0] = h2f_((unsigned short)(q0.x & 0xffffu)) + h2f_((unsigned short)(q1.x & 0xffffu)) * INV4096;
        xs[1] = h2f_((unsigned short)(q0.x >> 16))     + h2f_((unsigned short)(q1.x >> 16)) * INV4096;
        xs[2] = h2f_((unsigned short)(q0.y & 0xffffu)) + h2f_((unsigned short)(q1.y & 0xffffu)) * INV4096;
        xs[3] = h2f_((unsigned short)(q0.y >> 16))     + h2f_((unsigned short)(q1.y >> 16)) * INV4096;
        xs[4] = h2f_((unsigned short)(q0.z & 0xffffu)) + h2f_((unsigned short)(q1.z & 0xffffu)) * INV4096;
        xs[5] = h2f_((unsigned short)(q0.z >> 16))     + h2f_((unsigned short)(q1.z >> 16)) * INV4096;
        xs[6] = h2f_((unsigned short)(q0.w & 0xffffu)) + h2f_((unsigned short)(q1.w & 0xffffu)) * INV4096;
        xs[7] = h2f_((unsigned short)(q0.w >> 16))     + h2f_((unsigned short)(q1.w >> 16)) * INV4096;
        float pdf = 0.f, plo = 0.f, psc = 0.f;
        #pragma unroll
        for (int e = 0; e < 8; e++) {
          pdf += xs[e] * wd[e];
          plo += xs[e] * wl[e];
          psc += xs[e] * ws[e];
        }
        #pragma unroll
        for (int off2 = 1; off2 < 64; off2 <<= 1) {
          pdf += __shfl_xor(pdf, off2, 64);
          plo += __shfl_xor(plo, off2, 64);
          psc += __shfl_xor(psc, off2, 64);
        }
        if (lane == i) { adf = pdf; alo = plo; asc = psc; }
      }
      if (lane < 4) {
        int s = sbase + lane;
        float df = 2.0f + softplus_(adf + b_df[0]);
        float loc = alo + b_loc[0];
        float sc = softplus_(asc + b_sc[0]);
        float eps = sample_t_eps_(k, s, df);
        float smp = (loc + sc * eps) * scale;
        out[(size_t)s * PRED + k] = smp;
        tgt[s] = smp;
      }
    }
  }
}

// ------------------------------- launcher ----------------------------------
extern "C" void kernel_launch(void* const* d_in, const int* in_sizes, int n_in,
                              void* d_out, int out_size, void* d_ws, size_t ws_size,
                              hipStream_t stream) {
  const float* x      = (const float*)d_in[0];
  const float* x_mark = (const float*)d_in[1];
  const float* y_mark = (const float*)d_in[2];
  const float* W_emb  = (const float*)d_in[4];
  const float* b_emb  = (const float*)d_in[5];
  const float* W_ih   = (const float*)d_in[6];
  const float* W_hh   = (const float*)d_in[7];
  const float* b_ih   = (const float*)d_in[8];
  const float* b_hh   = (const float*)d_in[9];
  const float* W_df   = (const float*)d_in[10];
  const float* b_df   = (const float*)d_in[11];
  const float* W_loc  = (const float*)d_in[12];
  const float* b_loc  = (const float*)d_in[13];
  const float* W_sc   = (const float*)d_in[14];
  const float* b_sc   = (const float*)d_in[15];
  float* out = (float*)d_out;

  float* w = (float*)d_ws;
  unsigned short* h2_a = (unsigned short*)(w);                 // 2*8192*512 sh
  unsigned short* h2_b = (unsigned short*)(w + 4194304);       // 2*8192*512 sh
  unsigned short* Wr   = (unsigned short*)(w + 8388608);       // 2*1536*512 sh
  float* enc_gi = w + 9175040;              // 336*1536
  float* giy    = w + 9691136;              // 48*1536
  float* tfe    = w + 9764864;              // 336*40
  float* emb_y  = w + 9778304;              // 48*40
  float* ghbuf  = w + 9780224;              // 2*1536
  float* h_T    = w + 9783296;              // 512
  unsigned short* sT = (unsigned short*)(w + 9783808);  // 2*512 sh
  float* tgt    = w + 9784320;              // 8192
  float* scale_p = w + 9792512;             // 1
  unsigned* eflags = (unsigned*)(w + 9792516);  // 48*16
  unsigned* dflags = (unsigned*)(w + 9793540);  // 512*16 + 16 (incl. xmask)
  unsigned* xmask  = dflags + DEC_BLOCKS * 16;  // 8 uints

  prep_kernel<<<1, 256, 0, stream>>>(x, x_mark, y_mark, W_emb, b_emb,
                                     scale_p, tfe, emb_y, eflags, dflags);
  enc_gi_kernel<<<HIST, 256, 0, stream>>>(x, tfe, W_ih, b_ih, scale_p, enc_gi);
  giy_kernel<<<PRED, 256, 0, stream>>>(emb_y, W_ih, b_ih, giy);
  wsplit_kernel<<<1536, 256, 0, stream>>>(W_hh, Wr);
  enc_gru_kernel<<<ENC_BLOCKS, 256, 0, stream>>>(enc_gi, W_hh, b_hh, ghbuf,
                                                 eflags, h_T);
  hsplit_kernel<<<1, 256, 0, stream>>>(h_T, sT);
  h2bcast_kernel<<<S_N, 128, 0, stream>>>(sT, h2_a);

  dec_persistent<<<DEC_BLOCKS, 256, 0, stream>>>(
      h2_a, h2_b, Wr, giy, b_hh, W_ih, x, W_df, b_df, W_loc, b_loc,
      W_sc, b_sc, scale_p, tgt, out, dflags, xmask);
}

// Round 9
// 5616.860 us; speedup vs baseline: 1.6767x; 1.6767x over previous
//
#include <hip/hip_runtime.h>
#include <cmath>

// ---------------------------------------------------------------------------
// DeepAR sampling on MI355X. Round 9: revert to round-6 structure (persistent
// fusion of r7/r8 regressed twice; structural HBM traffic, not fences), plus:
//  - head dots computed as split-K partials in dec_gru's epilogue (exact fp32
//    h, deterministic shfl-butterfly + fixed wn/jb order). dec_head becomes a
//    1.5 MB partial reduce + RNG: kills its 16 MB/step h2 re-read.
//  - h2_out stored with __builtin_nontemporal_store: stops evicting Wr from
//    per-XCD L2 (r8 showed Wr re-fetch ~24 MB/step from 7 MB live vs 4 MB L2).
//  - encoder + GRU GEMM (MFMA order) bit-identical to round 6.
// ---------------------------------------------------------------------------

#define JAX_PARTITIONABLE 1

#define HIDDEN 512
#define EMB 40
#define HIST 336
#define PRED 48
#define S_N 8192
#define ENC_BLOCKS 48

#define HPLANE (8192 * 512)     // shorts per h split plane
#define WPLANE (1536 * 512)     // shorts per W split plane
#define INV4096 (1.0f / 4096.0f)

typedef __attribute__((ext_vector_type(8))) _Float16 half8;
typedef __attribute__((ext_vector_type(4))) float f32x4;

// ------------------------------- threefry ----------------------------------
struct KeyPair { unsigned a, b; };

__device__ __forceinline__ unsigned rotl32_(unsigned v, unsigned s) {
  return (v << s) | (v >> (32u - s));
}

__device__ __forceinline__ KeyPair tf2x32(KeyPair k, unsigned x0, unsigned x1) {
  unsigned ks0 = k.a, ks1 = k.b, ks2 = ks0 ^ ks1 ^ 0x1BD11BDAu;
  x0 += ks0; x1 += ks1;
#define TF_R(r) { x0 += x1; x1 = rotl32_(x1, r); x1 ^= x0; }
  TF_R(13u) TF_R(15u) TF_R(26u) TF_R(6u)  x0 += ks1; x1 += ks2 + 1u;
  TF_R(17u) TF_R(29u) TF_R(16u) TF_R(24u) x0 += ks2; x1 += ks0 + 2u;
  TF_R(13u) TF_R(15u) TF_R(26u) TF_R(6u)  x0 += ks0; x1 += ks1 + 3u;
  TF_R(17u) TF_R(29u) TF_R(16u) TF_R(24u) x0 += ks1; x1 += ks2 + 4u;
  TF_R(13u) TF_R(15u) TF_R(26u) TF_R(6u)  x0 += ks2; x1 += ks0 + 5u;
#undef TF_R
  KeyPair r; r.a = x0; r.b = x1; return r;
}

__device__ __forceinline__ void split2_(KeyPair key, KeyPair& r0, KeyPair& r1) {
#if JAX_PARTITIONABLE
  r0 = tf2x32(key, 0u, 0u);
  r1 = tf2x32(key, 0u, 1u);
#else
  KeyPair p0 = tf2x32(key, 0u, 2u);
  KeyPair p1 = tf2x32(key, 1u, 3u);
  r0.a = p0.a; r0.b = p1.a;
  r1.a = p0.b; r1.b = p1.b;
#endif
}

__device__ __forceinline__ void split3_(KeyPair key, KeyPair& r0, KeyPair& r1, KeyPair& r2) {
#if JAX_PARTITIONABLE
  r0 = tf2x32(key, 0u, 0u);
  r1 = tf2x32(key, 0u, 1u);
  r2 = tf2x32(key, 0u, 2u);
#else
  KeyPair p0 = tf2x32(key, 0u, 3u);
  KeyPair p1 = tf2x32(key, 1u, 4u);
  KeyPair p2 = tf2x32(key, 2u, 5u);
  r0.a = p0.a; r0.b = p1.a;
  r1.a = p2.a; r1.b = p0.b;
  r2.a = p1.b; r2.b = p2.b;
#endif
}

__device__ __forceinline__ unsigned scalar_bits_(KeyPair key) {
#if JAX_PARTITIONABLE
  KeyPair p = tf2x32(key, 0u, 0u);
  return p.a ^ p.b;
#else
  return tf2x32(key, 0u, 0u).a;
#endif
}

__device__ __forceinline__ unsigned batch_bits_8192_(KeyPair key, int s) {
#if JAX_PARTITIONABLE
  KeyPair p = tf2x32(key, 0u, (unsigned)s);
  return p.a ^ p.b;
#else
  if (s < 4096) return tf2x32(key, (unsigned)s, (unsigned)(4096 + s)).a;
  return tf2x32(key, (unsigned)(s - 4096), (unsigned)s).b;
#endif
}

__device__ __forceinline__ KeyPair subkey_of_8192_(KeyPair key, int s) {
#if JAX_PARTITIONABLE
  return tf2x32(key, 0u, (unsigned)s);
#else
  KeyPair r;
  if (s < 4096) {
    r.a = tf2x32(key, (unsigned)(2 * s),     (unsigned)(8192 + 2 * s)).a;
    r.b = tf2x32(key, (unsigned)(2 * s + 1), (unsigned)(8192 + 2 * s + 1)).a;
  } else {
    int m = 2 * s - 8192;
    r.a = tf2x32(key, (unsigned)m,       (unsigned)(m + 8192)).b;
    r.b = tf2x32(key, (unsigned)(m + 1), (unsigned)(m + 1 + 8192)).b;
  }
  return r;
#endif
}

// ------------------------- fp32 numerics (XLA-matched) ---------------------
__device__ __forceinline__ float acc_logf_(float x) {
  return (float)log((double)x);
}
__device__ __forceinline__ float acc_expf_(float x) {
  return (float)exp((double)x);
}

__device__ __forceinline__ float bits_to_uniform01_(unsigned bits) {
  return __uint_as_float((bits >> 9) | 0x3F800000u) - 1.0f;
}

__device__ __forceinline__ float xla_log1pf_(float t) {
  #pragma clang fp contract(off)
  float small_ = (1.0f + (-0.5f) * t) * t;
  float large_ = acc_logf_(t + 1.0f);
  return (fabsf(t) < 1e-4f) ? small_ : large_;
}

__device__ float xla_erfinv_(float x) {
  #pragma clang fp contract(off)
  float w = -xla_log1pf_(-(x * x));
  float p;
  if (w < 5.0f) {
    float ww = w - 2.5f;
    p = 2.81022636e-08f;
    p = 3.43273939e-07f + p * ww;
    p = -3.5233877e-06f + p * ww;
    p = -4.39150654e-06f + p * ww;
    p = 0.00021858087f + p * ww;
    p = -0.00125372503f + p * ww;
    p = -0.00417768164f + p * ww;
    p = 0.246640727f + p * ww;
    p = 1.50140941f + p * ww;
  } else {
    float ww = sqrtf(w) - 3.0f;
    p = -0.000200214257f;
    p = 0.000100950558f + p * ww;
    p = 0.00134934322f + p * ww;
    p = -0.00367342844f + p * ww;
    p = 0.00573950773f + p * ww;
    p = -0.0076224613f + p * ww;
    p = 0.00943887047f + p * ww;
    p = 1.00167406f + p * ww;
    p = 2.83297682f + p * ww;
  }
  return p * x;
}

__device__ float bits_to_normal_(unsigned bits) {
  #pragma clang fp contract(off)
  const float lo = __uint_as_float(0xBF7FFFFFu);
  float f = bits_to_uniform01_(bits);
  float u = f * 2.0f + lo;
  u = fmaxf(lo, u);
  return __uint_as_float(0x3FB504F3u) * xla_erfinv_(u);
}

__device__ __forceinline__ float softplus_(float x) {
  #pragma clang fp contract(off)
  float amax = fmaxf(x, 0.0f);
  float e = acc_expf_(-fabsf(x));
  return amax + xla_log1pf_(e);
}

__device__ __forceinline__ float sigmoid_(float v) { return 1.0f / (1.0f + expf(-v)); }

// fp16 split helpers (round-to-nearest-even via cast)
__device__ __forceinline__ unsigned short f2h_(float f) {
  _Float16 h = (_Float16)f;
  return __builtin_bit_cast(unsigned short, h);
}
__device__ __forceinline__ float h2f_(unsigned short b) {
  return (float)__builtin_bit_cast(_Float16, b);
}

// ------------------------- gamma / student-t sampler -----------------------
__device__ float gamma_sample_(KeyPair gkey, float alpha) {
  #pragma clang fp contract(off)
  const float third = 0.33333334f;
  float d = alpha - third;
  float c = third / sqrtf(d);
  KeyPair key, boost_sub;
  split2_(gkey, key, boost_sub);
  (void)boost_sub;
  float X = 0.0f, V = 1.0f, U = 2.0f;
  for (int guard = 0; guard < 1024; guard++) {
    float X2 = X * X;
    float sq = 1.0f - 0.0331f * (X2 * X2);
    bool cont = false;
    if (U >= sq) {
      float lhs = acc_logf_(U);
      float rhs = (X * 0.5f) + (d * ((1.0f - V) + acc_logf_(V)));
      cont = (lhs >= rhs);
    }
    if (!cont) break;
    KeyPair nkey, xkey, Ukey;
    split3_(key, nkey, xkey, Ukey);
    key = nkey;
    float x, v;
    KeyPair kk = xkey;
    do {
      KeyPair knew, sub;
      split2_(kk, knew, sub);
      kk = knew;
      x = bits_to_normal_(scalar_bits_(sub));
      v = 1.0f + x * c;
    } while (v <= 0.0f);
    X = x * x;
    V = (v * v) * v;
    U = bits_to_uniform01_(scalar_bits_(Ukey));
  }
  return d * V;
}

__device__ float sample_t_eps_(int k, int s, float df) {
  #pragma clang fp contract(off)
  KeyPair base; base.a = 0u; base.b = 42u;
  KeyPair tkey = tf2x32(base, 0u, (unsigned)k);
  KeyPair key_n, key_g;
  split2_(tkey, key_n, key_g);
  float n = bits_to_normal_(batch_bits_8192_(key_n, s));
  KeyPair gkey = subkey_of_8192_(key_g, s);
  float half_df = df * 0.5f;
  float g = gamma_sample_(gkey, half_df);
  return n * sqrtf(half_df / g);
}

// ------------------------------- kernels -----------------------------------

__global__ __launch_bounds__(256) void prep_kernel(
    const float* __restrict__ x, const float* __restrict__ x_mark,
    const float* __restrict__ y_mark, const float* __restrict__ W_emb,
    const float* __restrict__ b_emb, float* __restrict__ scale_p,
    float* __restrict__ tfe, float* __restrict__ emb_y,
    unsigned* __restrict__ flags) {
  int tid = threadIdx.x;
  if (tid == 0) {
    float s = 0.0f;
    for (int t = 0; t < HIST; t++) s += fabsf(x[t]);
    float m = s / 336.0f;
    scale_p[0] = fmaxf(m, 1e-5f);
  }
  for (int i = tid; i < ENC_BLOCKS * 16; i += 256) flags[i] = 0u;
  for (int idx = tid; idx < HIST * EMB; idx += 256) {
    int t = idx / EMB, e = idx % EMB;
    float a = b_emb[e];
    for (int f = 0; f < 4; f++) a += x_mark[t * 4 + f] * W_emb[e * 4 + f];
    tfe[idx] = a;
  }
  for (int idx = tid; idx < PRED * EMB; idx += 256) {
    int kk = idx / EMB, e = idx % EMB;
    float a = b_emb[e];
    for (int f = 0; f < 4; f++) a += y_mark[kk * 4 + f] * W_emb[e * 4 + f];
    emb_y[idx] = a;
  }
}

__global__ __launch_bounds__(256) void enc_gi_kernel(
    const float* __restrict__ x, const float* __restrict__ tfe,
    const float* __restrict__ W_ih, const float* __restrict__ b_ih,
    const float* __restrict__ scale_p, float* __restrict__ enc_gi) {
  __shared__ float fe[EMB];
  __shared__ float xs_s;
  int t = blockIdx.x;
  int tid = threadIdx.x;
  if (tid < EMB) fe[tid] = tfe[t * EMB + tid];
  if (tid == 0) xs_s = x[t] / scale_p[0];
  __syncthreads();
  float xs = xs_s;
  for (int r = tid; r < 3 * HIDDEN; r += 256) {
    const float* wr = W_ih + (size_t)r * 41;
    float a = b_ih[r] + wr[0] * xs;
    #pragma unroll
    for (int e = 0; e < EMB; e++) a += wr[1 + e] * fe[e];
    enc_gi[(size_t)t * 1536 + r] = a;
  }
}

__global__ __launch_bounds__(256) void giy_kernel(
    const float* __restrict__ emb_y, const float* __restrict__ W_ih,
    const float* __restrict__ b_ih, float* __restrict__ giy) {
  __shared__ float fe[EMB];
  int k = blockIdx.x;
  int tid = threadIdx.x;
  if (tid < EMB) fe[tid] = emb_y[k * EMB + tid];
  __syncthreads();
  for (int r = tid; r < 3 * HIDDEN; r += 256) {
    const float* wr = W_ih + (size_t)r * 41;
    float a = b_ih[r];
    #pragma unroll
    for (int e = 0; e < EMB; e++) a += wr[1 + e] * fe[e];
    giy[(size_t)k * 1536 + r] = a;
  }
}

// W_hh -> 2 fp16 split planes: Wr[sp][jb*96 + g*32 + jl][k], row = g*512+jb*32+jl
__global__ __launch_bounds__(256) void wsplit_kernel(
    const float* __restrict__ W_hh, unsigned short* __restrict__ Wr) {
  int row = blockIdx.x;                 // 0..1535
  int g = row >> 9;
  int jg = row & 511;
  int jb = jg >> 5, jl = jg & 31;
  size_t dst = ((size_t)jb * 96 + g * 32 + jl) * 512;
  for (int k = threadIdx.x; k < 512; k += 256) {
    float w = W_hh[(size_t)row * 512 + k];
    unsigned short g0 = f2h_(w);
    float r1 = (w - h2f_(g0)) * 4096.0f;
    unsigned short g1 = f2h_(r1);
    Wr[dst + k] = g0;
    Wr[WPLANE + dst + k] = g1;
  }
}

// split h_T (512) into sT[2][512] fp16 planes
__global__ __launch_bounds__(256) void hsplit_kernel(
    const float* __restrict__ h_T, unsigned short* __restrict__ sT) {
  int i = threadIdx.x;
  for (int j = i; j < 512; j += 256) {
    float v = h_T[j];
    unsigned short f0 = f2h_(v);
    float r1 = (v - h2f_(f0)) * 4096.0f;
    sT[j] = f0;
    sT[512 + j] = f2h_(r1);
  }
}

// broadcast sT rows into h2[2][8192][512]
__global__ __launch_bounds__(128) void h2bcast_kernel(
    const unsigned short* __restrict__ sT, unsigned short* __restrict__ h2) {
  int row = blockIdx.x;
  int tid = threadIdx.x;
  int sp = tid >> 6, c = tid & 63;
  ((uint4*)(h2 + (size_t)sp * HPLANE + (size_t)row * 512))[c] =
      ((const uint4*)(sT + sp * 512))[c];
}

// persistent encoder GRU; round-3 flag-array grid barrier (unchanged)
__global__ __launch_bounds__(256) void enc_gru_kernel(
    const float* __restrict__ enc_gi, const float* __restrict__ W_hh,
    const float* __restrict__ b_hh, float* __restrict__ ghbuf,
    unsigned* __restrict__ flags, float* __restrict__ h_T) {
  __shared__ __align__(16) float hs[HIDDEN];
  int tid = threadIdx.x;
  int gtid = blockIdx.x * 256 + tid;
  int row = gtid >> 3;
  int sub = gtid & 7;

  float w[64];
  const float* wp = W_hh + (size_t)row * HIDDEN + sub * 64;
  #pragma unroll
  for (int i = 0; i < 16; i++) {
    float4 v = *(const float4*)(wp + 4 * i);
    w[4 * i + 0] = v.x; w[4 * i + 1] = v.y; w[4 * i + 2] = v.z; w[4 * i + 3] = v.w;
  }
  if (tid < 128) *(float4*)&hs[tid * 4] = make_float4(0.f, 0.f, 0.f, 0.f);
  float bhr0 = b_hh[tid],       bhz0 = b_hh[512 + tid],  bhn0 = b_hh[1024 + tid];
  float bhr1 = b_hh[256 + tid], bhz1 = b_hh[768 + tid],  bhn1 = b_hh[1280 + tid];
  __syncthreads();

  for (int t = 0; t < HIST; t++) {
    float p = 0.0f;
    const float4* hv = (const float4*)&hs[sub * 64];
    #pragma unroll
    for (int i = 0; i < 16; i++) {
      float4 v = hv[i];
      p += w[4 * i + 0] * v.x + w[4 * i + 1] * v.y +
           w[4 * i + 2] * v.z + w[4 * i + 3] * v.w;
    }
    p += __shfl_xor(p, 1, 64);
    p += __shfl_xor(p, 2, 64);
    p += __shfl_xor(p, 4, 64);
    int par = t & 1;
    if (sub == 0)
      __hip_atomic_store(&ghbuf[par * 1536 + row], p, __ATOMIC_RELAXED,
                         __HIP_MEMORY_SCOPE_AGENT);
    __syncthreads();
    if (tid == 0)
      __hip_atomic_store(&flags[blockIdx.x * 16], (unsigned)(t + 1),
                         __ATOMIC_RELEASE, __HIP_MEMORY_SCOPE_AGENT);
    if (tid < ENC_BLOCKS) {
      while (__hip_atomic_load(&flags[tid * 16], __ATOMIC_ACQUIRE,
                               __HIP_MEMORY_SCOPE_AGENT) < (unsigned)(t + 1))
        __builtin_amdgcn_s_sleep(1);
    }
    __syncthreads();
    float hn0, hn1;
    {
      int j = tid;
      float ghr = __hip_atomic_load(&ghbuf[par * 1536 + j], __ATOMIC_RELAXED, __HIP_MEMORY_SCOPE_AGENT);
      float ghz = __hip_atomic_load(&ghbuf[par * 1536 + 512 + j], __ATOMIC_RELAXED, __HIP_MEMORY_SCOPE_AGENT);
      float ghn = __hip_atomic_load(&ghbuf[par * 1536 + 1024 + j], __ATOMIC_RELAXED, __HIP_MEMORY_SCOPE_AGENT);
      float gir = enc_gi[(size_t)t * 1536 + j];
      float giz = enc_gi[(size_t)t * 1536 + 512 + j];
      float gin = enc_gi[(size_t)t * 1536 + 1024 + j];
      float r = sigmoid_(gir + (ghr + bhr0));
      float z = sigmoid_(giz + (ghz + bhz0));
      float n = tanhf(gin + r * (ghn + bhn0));
      hn0 = (1.0f - z) * n + z * hs[j];
    }
    {
      int j = tid + 256;
      float ghr = __hip_atomic_load(&ghbuf[par * 1536 + j], __ATOMIC_RELAXED, __HIP_MEMORY_SCOPE_AGENT);
      float ghz = __hip_atomic_load(&ghbuf[par * 1536 + 512 + j], __ATOMIC_RELAXED, __HIP_MEMORY_SCOPE_AGENT);
      float ghn = __hip_atomic_load(&ghbuf[par * 1536 + 1024 + j], __ATOMIC_RELAXED, __HIP_MEMORY_SCOPE_AGENT);
      float gir = enc_gi[(size_t)t * 1536 + j];
      float giz = enc_gi[(size_t)t * 1536 + 512 + j];
      float gin = enc_gi[(size_t)t * 1536 + 1024 + j];
      float r = sigmoid_(gir + (ghr + bhr1));
      float z = sigmoid_(giz + (ghz + bhz1));
      float n = tanhf(gin + r * (ghn + bhn1));
      hn1 = (1.0f - z) * n + z * hs[j];
    }
    hs[tid] = hn0;
    hs[tid + 256] = hn1;
    __syncthreads();
  }
  if (blockIdx.x == 0 && tid < 128)
    *(float4*)&h_T[tid * 4] = *(float4*)&hs[tid * 4];
}

// ---------------------------------------------------------------------------
// Decoder GRU step via fp16 MFMA, 2-split x 3 products (round-6 structure).
// A double-buffered in LDS (1 barrier/iter); B-frags direct global->reg,
// prefetched one K-iter ahead. NEW: epilogue computes split-K head partials
// (exact fp32 h, deterministic reduce) and nt-stores h2_out.
// ---------------------------------------------------------------------------
__global__ __launch_bounds__(256, 2) void dec_gru_mfma(
    const unsigned short* __restrict__ h2_in,   // [2][8192][512] fp16
    const unsigned short* __restrict__ Wr,      // [2][16 jb][96][512] fp16
    const float* __restrict__ giy_k, const float* __restrict__ b_hh,
    const float* __restrict__ W_ih, const float* __restrict__ tgt,
    int tgt_is_x, unsigned short* __restrict__ h2_out,
    const float* __restrict__ W_df, const float* __restrict__ W_loc,
    const float* __restrict__ W_sc, float* __restrict__ partials) {
  __shared__ unsigned short As[2][2][128][32];   // [buf][plane][row][col]
  int b_ = blockIdx.x;
  int xcd = b_ & 7, slot = b_ >> 3;          // slot 0..127
  int mb = xcd * 8 + (slot & 7);             // 0..63
  int jb = slot >> 3;                        // 0..15
  int tid = threadIdx.x;
  int lane = tid & 63;
  int wave = tid >> 6;
  int wm = wave >> 1, wn = wave & 1;
  int s0 = mb * 128;
  int q = lane >> 4, c = lane & 15;

  f32x4 accm[4][3], accc[4][3];
  #pragma unroll
  for (int i = 0; i < 4; i++)
    #pragma unroll
    for (int g = 0; g < 3; g++) {
      accm[i][g] = (f32x4){0.f, 0.f, 0.f, 0.f};
      accc[i][g] = (f32x4){0.f, 0.f, 0.f, 0.f};
    }

  float hold[4][4];
  #pragma unroll
  for (int i = 0; i < 4; i++)
    #pragma unroll
    for (int r = 0; r < 4; r++) hold[i][r] = 0.f;

  // per-thread A staging map (4 chunks covering 2 planes x 128 rows x 32 cols)
  int asp[4], arow[4], acol[4];
  #pragma unroll
  for (int r = 0; r < 4; r++) {
    int a = r * 256 + tid;
    asp[r] = a >> 9;
    int rem = a & 511;
    arow[r] = rem >> 2;
    acol[r] = rem & 3;
  }

  // B-frag base address (row jb*96 + g*32 + wn*16 + c, col chunk q)
  const unsigned short* Bbase =
      Wr + ((size_t)jb * 96 + wn * 16 + c) * 512 + q * 8;

  // initial stage A (kb=0) into buffer 0
  #pragma unroll
  for (int r = 0; r < 4; r++) {
    uint4 v = *(const uint4*)(h2_in + (size_t)asp[r] * HPLANE +
                              (size_t)(s0 + arow[r]) * 512 + acol[r] * 8);
    *(uint4*)&As[0][asp[r]][arow[r]][(acol[r] ^ (arow[r] & 3)) * 8] = v;
  }
  // initial B (kb=0)
  half8 Bcur[3][2];
  #pragma unroll
  for (int g = 0; g < 3; g++) {
    Bcur[g][0] = *(const half8*)(Bbase + (size_t)g * 32 * 512);
    Bcur[g][1] = *(const half8*)(Bbase + WPLANE + (size_t)g * 32 * 512);
  }
  __syncthreads();

  int cur = 0;
  for (int kbi = 0; kbi < 16; kbi++) {
    int kb = kbi * 32;
    // prefetch next A + B
    uint4 Areg[4];
    half8 Bn[3][2];
    if (kbi < 15) {
      #pragma unroll
      for (int r = 0; r < 4; r++)
        Areg[r] = *(const uint4*)(h2_in + (size_t)asp[r] * HPLANE +
                                  (size_t)(s0 + arow[r]) * 512 + kb + 32 +
                                  acol[r] * 8);
      #pragma unroll
      for (int g = 0; g < 3; g++) {
        Bn[g][0] = *(const half8*)(Bbase + (size_t)g * 32 * 512 + kb + 32);
        Bn[g][1] = *(const half8*)(Bbase + WPLANE + (size_t)g * 32 * 512 + kb + 32);
      }
    }
    // capture h_old while its k-slice sits in LDS
    if (kbi == jb) {
      int cc = wn * 16 + c;
      #pragma unroll
      for (int i = 0; i < 4; i++)
        #pragma unroll
        for (int reg = 0; reg < 4; reg++) {
          int m = wm * 64 + i * 16 + q * 4 + reg;
          int idx = (((cc >> 3) ^ (m & 3)) << 3) + (cc & 7);
          hold[i][reg] = h2f_(As[cur][0][m][idx]) +
                         h2f_(As[cur][1][m][idx]) * INV4096;
        }
    }
    // compute (MFMA order identical to round 6)
    #pragma unroll
    for (int i = 0; i < 4; i++) {
      int m = wm * 64 + i * 16 + c;
      half8 a0 = *(const half8*)&As[cur][0][m][(q ^ (c & 3)) * 8];
      half8 a1 = *(const half8*)&As[cur][1][m][(q ^ (c & 3)) * 8];
      #pragma unroll
      for (int g = 0; g < 3; g++) {
        accm[i][g] = __builtin_amdgcn_mfma_f32_16x16x32_f16(a0, Bcur[g][0], accm[i][g], 0, 0, 0);
        accc[i][g] = __builtin_amdgcn_mfma_f32_16x16x32_f16(a0, Bcur[g][1], accc[i][g], 0, 0, 0);
        accc[i][g] = __builtin_amdgcn_mfma_f32_16x16x32_f16(a1, Bcur[g][0], accc[i][g], 0, 0, 0);
      }
    }
    // store prefetched A into the other buffer
    if (kbi < 15) {
      #pragma unroll
      for (int r = 0; r < 4; r++)
        *(uint4*)&As[cur ^ 1][asp[r]][arow[r]][(acol[r] ^ (arow[r] & 3)) * 8] =
            Areg[r];
      #pragma unroll
      for (int g = 0; g < 3; g++) {
        Bcur[g][0] = Bn[g][0];
        Bcur[g][1] = Bn[g][1];
      }
    }
    __syncthreads();
    cur ^= 1;
  }

  // epilogue: gates + h update + nt fp16 2-split store + head partials
  float* pb = (float*)&As[0][0][0][0];   // reuse LDS: 4*64*3 floats
  {
    int j = jb * 32 + wn * 16 + c;
    float gyr = giy_k[j], gyz = giy_k[512 + j], gyn = giy_k[1024 + j];
    float w0r = W_ih[(size_t)j * 41];
    float w0z = W_ih[(size_t)(512 + j) * 41];
    float w0n = W_ih[(size_t)(1024 + j) * 41];
    float bhr = b_hh[j], bhz = b_hh[512 + j], bhn = b_hh[1024 + j];
    float wdj = W_df[j], wlj = W_loc[j], wsj = W_sc[j];
    #pragma unroll
    for (int i = 0; i < 4; i++) {
      #pragma unroll
      for (int reg = 0; reg < 4; reg++) {
        int s = s0 + wm * 64 + i * 16 + q * 4 + reg;
        float tg = tgt_is_x ? tgt[HIST - 1] : tgt[s];
        size_t off = (size_t)s * 512 + j;
        float h_old = hold[i][reg];
        float ghr = accm[i][0][reg] + accc[i][0][reg] * INV4096;
        float ghz = accm[i][1][reg] + accc[i][1][reg] * INV4096;
        float ghn = accm[i][2][reg] + accc[i][2][reg] * INV4096;
        float gr = (gyr + w0r * tg) + (ghr + bhr);
        float gz = (gyz + w0z * tg) + (ghz + bhz);
        float gn_i = gyn + w0n * tg;
        float gn_h = ghn + bhn;
        float r_ = sigmoid_(gr);
        float z_ = sigmoid_(gz);
        float n_ = tanhf(gn_i + r_ * gn_h);
        float hn = (1.0f - z_) * n_ + z_ * h_old;
        unsigned short f0 = f2h_(hn);
        float r1 = (hn - h2f_(f0)) * 4096.0f;
        __builtin_nontemporal_store(f0, &h2_out[off]);
        __builtin_nontemporal_store(f2h_(r1), &h2_out[HPLANE + off]);
        // head partial products (exact fp32 h), reduce over the 16 c-lanes
        float vd = hn * wdj, vl = hn * wlj, vs = hn * wsj;
        #pragma unroll
        for (int o = 1; o < 16; o <<= 1) {
          vd += __shfl_xor(vd, o, 64);
          vl += __shfl_xor(vl, o, 64);
          vs += __shfl_xor(vs, o, 64);
        }
        if (c == 0) {
          int sl = i * 16 + q * 4 + reg;               // 0..63
          int bix = ((wm * 2 + wn) * 64 + sl) * 3;
          pb[bix + 0] = vd; pb[bix + 1] = vl; pb[bix + 2] = vs;
        }
      }
    }
  }
  __syncthreads();
  // cross-wn add (fixed order: wn0 + wn1) + global partial store
  if (tid < 128) {
    int wmh = tid >> 6, sl = tid & 63;
    int ia = (wmh * 2 + 0) * 192 + sl * 3;
    int ib = ia + 192;
    int s = s0 + wmh * 64 + sl;
    size_t pofs = (size_t)s * 48 + jb * 3;
    partials[pofs + 0] = pb[ia + 0] + pb[ib + 0];
    partials[pofs + 1] = pb[ia + 1] + pb[ib + 1];
    partials[pofs + 2] = pb[ia + 2] + pb[ib + 2];
  }
}

// heads + student-t sampling from split-K partials (jb-ascending reduce).
__global__ __launch_bounds__(64) void dec_head_kernel(
    const float* __restrict__ partials, const float* __restrict__ b_df,
    const float* __restrict__ b_loc, const float* __restrict__ b_sc,
    const float* __restrict__ scale_p, float* __restrict__ tgt,
    float* __restrict__ out, int k) {
  #pragma clang fp contract(off)
  int s = blockIdx.x * 64 + threadIdx.x;
  const float* p = partials + (size_t)s * 48;
  float adf = 0.f, alo = 0.f, asc = 0.f;
  #pragma unroll
  for (int jb = 0; jb < 16; jb++) {
    adf += p[jb * 3 + 0];
    alo += p[jb * 3 + 1];
    asc += p[jb * 3 + 2];
  }
  float df = 2.0f + softplus_(adf + b_df[0]);
  float loc = alo + b_loc[0];
  float sc = softplus_(asc + b_sc[0]);
  float eps = sample_t_eps_(k, s, df);
  float smp = (loc + sc * eps) * scale_p[0];
  out[(size_t)s * PRED + k] = smp;
  tgt[s] = smp;
}

// ------------------------------- launcher ----------------------------------
extern "C" void kernel_launch(void* const* d_in, const int* in_sizes, int n_in,
                              void* d_out, int out_size, void* d_ws, size_t ws_size,
                              hipStream_t stream) {
  const float* x      = (const float*)d_in[0];
  const float* x_mark = (const float*)d_in[1];
  const float* y_mark = (const float*)d_in[2];
  const float* W_emb  = (const float*)d_in[4];
  const float* b_emb  = (const float*)d_in[5];
  const float* W_ih   = (const float*)d_in[6];
  const float* W_hh   = (const float*)d_in[7];
  const float* b_ih   = (const float*)d_in[8];
  const float* b_hh   = (const float*)d_in[9];
  const float* W_df   = (const float*)d_in[10];
  const float* b_df   = (const float*)d_in[11];
  const float* W_loc  = (const float*)d_in[12];
  const float* b_loc  = (const float*)d_in[13];
  const float* W_sc   = (const float*)d_in[14];
  const float* b_sc   = (const float*)d_in[15];
  float* out = (float*)d_out;

  float* w = (float*)d_ws;
  unsigned short* h2_a = (unsigned short*)(w);                 // 2*8192*512 sh
  unsigned short* h2_b = (unsigned short*)(w + 4194304);       // 2*8192*512 sh
  unsigned short* Wr   = (unsigned short*)(w + 8388608);       // 2*1536*512 sh
  float* enc_gi = w + 9175040;              // 336*1536
  float* giy    = w + 9691136;              // 48*1536
  float* tfe    = w + 9764864;              // 336*40
  float* emb_y  = w + 9778304;              // 48*40
  float* ghbuf  = w + 9780224;              // 2*1536
  float* h_T    = w + 9783296;              // 512
  unsigned short* sT = (unsigned short*)(w + 9783808);  // 2*512 sh
  float* tgt    = w + 9784320;              // 8192
  float* scale_p = w + 9792512;             // 1
  unsigned* flags = (unsigned*)(w + 9792516);  // 48*16 ints
  float* partials = w + 9793540;            // 8192*48 floats (~1.57 MB)

  prep_kernel<<<1, 256, 0, stream>>>(x, x_mark, y_mark, W_emb, b_emb,
                                     scale_p, tfe, emb_y, flags);
  enc_gi_kernel<<<HIST, 256, 0, stream>>>(x, tfe, W_ih, b_ih, scale_p, enc_gi);
  giy_kernel<<<PRED, 256, 0, stream>>>(emb_y, W_ih, b_ih, giy);
  wsplit_kernel<<<1536, 256, 0, stream>>>(W_hh, Wr);
  enc_gru_kernel<<<ENC_BLOCKS, 256, 0, stream>>>(enc_gi, W_hh, b_hh, ghbuf,
                                                 flags, h_T);
  hsplit_kernel<<<1, 256, 0, stream>>>(h_T, sT);
  h2bcast_kernel<<<S_N, 128, 0, stream>>>(sT, h2_a);

  for (int k = 0; k < PRED; k++) {
    const unsigned short* h_in = (k % 2 == 0) ? h2_a : h2_b;
    unsigned short* h_o = (k % 2 == 0) ? h2_b : h2_a;
    dec_gru_mfma<<<1024, 256, 0, stream>>>(
        h_in, Wr, giy + (size_t)k * 1536, b_hh, W_ih,
        (k == 0) ? x : tgt, (k == 0) ? 1 : 0, h_o,
        W_df, W_loc, W_sc, partials);
    dec_head_kernel<<<S_N / 64, 64, 0, stream>>>(
        partials, b_df, b_loc, b_sc, scale_p, tgt, out, k);
  }
}